// Round 5
// baseline (470.550 us; speedup 1.0000x reference)
//
#include <hip/hip_runtime.h>
#include <hip/hip_bf16.h>

#define N_NODES 100000
#define N_EDGES 1600000
#define FDIM 128
#define NCLS 40
#define NCLS_PAD 48

#define SCAN_BLK 1024
#define SCAN_NB ((N_NODES + SCAN_BLK - 1) / SCAN_BLK)   // 98

#define NREG 8
#define REG_SZ (N_NODES / NREG)                         // 12500 nodes per region
#define CHUNKA 4096
#define NBLKA ((N_EDGES + CHUNKA - 1) / CHUNKA)         // 391 partition blocks
#define REGBLK 64                                       // blocks per region for reg-pinned kernels

typedef __attribute__((ext_vector_type(8))) short short8;
typedef __attribute__((ext_vector_type(4))) float f32x4;

__device__ __forceinline__ float bf2f(unsigned short u) {
    union { unsigned int i; float f; } v; v.i = ((unsigned int)u) << 16; return v.f;
}
__device__ __forceinline__ unsigned short f2bf(float f) {
    __hip_bfloat16 h = __float2bfloat16(f);
    return *reinterpret_cast<unsigned short*>(&h);
}

// ---------------- fp32 -> bf16 bulk convert (vectorized) ----------------
__global__ void k_cvt_bf16(const float4* __restrict__ in, ushort4* __restrict__ out, int n4) {
    int i = blockIdx.x * blockDim.x + threadIdx.x;
    if (i >= n4) return;
    float4 v = in[i];
    ushort4 o;
    o.x = f2bf(v.x); o.y = f2bf(v.y); o.z = f2bf(v.z); o.w = f2bf(v.w);
    out[i] = o;
}

// ---------------- radix phase 1: per-block per-region counts (no global atomics) ----------------
__global__ __launch_bounds__(256) void k_countA(const int* __restrict__ dst, int* __restrict__ bh) {
    __shared__ unsigned h[NREG];
    if (threadIdx.x < NREG) h[threadIdx.x] = 0u;
    __syncthreads();
    int base = blockIdx.x * CHUNKA;
    int end = base + CHUNKA; if (end > N_EDGES) end = N_EDGES;
    for (int e = base + threadIdx.x; e < end; e += 256)
        atomicAdd(&h[dst[e] / REG_SZ], 1u);
    __syncthreads();
    if (threadIdx.x < NREG) bh[blockIdx.x * NREG + threadIdx.x] = (int)h[threadIdx.x];
}

// ---------------- radix phase 2: scan of bh in bin-major order -> private segments ----------------
__global__ __launch_bounds__(1024) void k_scanA(const int* __restrict__ bh,
                                                int* __restrict__ obh, int* __restrict__ runbase) {
    __shared__ unsigned lds[1024];
    const int TOT = NBLKA * NREG;            // 3128
    const int SEG = (TOT + 1023) / 1024;     // 4
    int t = threadIdx.x;
    int lo = t * SEG;
    int hi = lo + SEG; if (hi > TOT) hi = TOT;
    unsigned s = 0;
    for (int i = lo; i < hi; ++i) { int r = i / NBLKA, b = i % NBLKA; s += (unsigned)bh[b * NREG + r]; }
    lds[t] = s;
    __syncthreads();
    for (int d = 1; d < 1024; d <<= 1) {
        unsigned add = (t >= d) ? lds[t - d] : 0u;
        __syncthreads();
        lds[t] += add;
        __syncthreads();
    }
    unsigned run = (t == 0) ? 0u : lds[t - 1];
    for (int i = lo; i < hi; ++i) {
        int r = i / NBLKA, b = i % NBLKA;
        obh[b * NREG + r] = (int)run;
        if (b == 0) runbase[r] = (int)run;
        run += (unsigned)bh[b * NREG + r];
    }
    if (t == 1023) runbase[NREG] = N_EDGES;
}

// ---------------- radix phase 3: write packed (dst,src) into private segments ----------------
__global__ __launch_bounds__(256) void k_binwrite(const int* __restrict__ src, const int* __restrict__ dst,
                                                  const int* __restrict__ obh,
                                                  unsigned long long* __restrict__ bpack) {
    __shared__ unsigned pos[NREG];
    if (threadIdx.x < NREG) pos[threadIdx.x] = (unsigned)obh[blockIdx.x * NREG + threadIdx.x];
    __syncthreads();
    int base = blockIdx.x * CHUNKA;
    int end = base + CHUNKA; if (end > N_EDGES) end = N_EDGES;
    for (int e = base + threadIdx.x; e < end; e += 256) {
        int d = dst[e];
        int r = d / REG_SZ;
        unsigned p = atomicAdd(&pos[r], 1u);
        bpack[p] = ((unsigned long long)(unsigned)d << 32) | (unsigned)src[e];
    }
}

// ---------------- region-pinned degree histogram (XCD-local atomics) ----------------
__global__ __launch_bounds__(256) void k_hist_reg(const unsigned long long* __restrict__ bpack,
                                                  const int* __restrict__ runbase,
                                                  unsigned* __restrict__ cnt) {
    int r = blockIdx.x & (NREG - 1);
    int bi = blockIdx.x >> 3;
    int lo = runbase[r], hi = runbase[r + 1];
    for (int i = lo + bi * 256 + threadIdx.x; i < hi; i += REGBLK * 256)
        atomicAdd(&cnt[(int)(bpack[i] >> 32)], 1u);
}

// ---------------- hierarchical exclusive scan ----------------
__global__ __launch_bounds__(SCAN_BLK) void k_scan_local(
        const unsigned* __restrict__ cnt, int* __restrict__ rowptr,
        unsigned* __restrict__ bsum) {
    __shared__ unsigned lds[SCAN_BLK];
    int t = threadIdx.x;
    int gid = blockIdx.x * SCAN_BLK + t;
    unsigned v = (gid < N_NODES) ? cnt[gid] : 0u;
    lds[t] = v;
    __syncthreads();
    for (int d = 1; d < SCAN_BLK; d <<= 1) {
        unsigned add = (t >= d) ? lds[t - d] : 0u;
        __syncthreads();
        lds[t] += add;
        __syncthreads();
    }
    if (gid < N_NODES) rowptr[gid] = (int)(lds[t] - v);   // exclusive within block
    if (t == SCAN_BLK - 1) bsum[blockIdx.x] = lds[t];
}

__global__ void k_scan_bsum(const unsigned* __restrict__ bsum, unsigned* __restrict__ boff) {
    __shared__ unsigned lds[128];
    int t = threadIdx.x;
    unsigned v = (t < SCAN_NB) ? bsum[t] : 0u;
    lds[t] = v;
    __syncthreads();
    for (int d = 1; d < 128; d <<= 1) {
        unsigned add = (t >= d) ? lds[t - d] : 0u;
        __syncthreads();
        lds[t] += add;
        __syncthreads();
    }
    if (t < SCAN_NB) boff[t] = lds[t] - v;
}

__global__ __launch_bounds__(SCAN_BLK) void k_scan_add(
        int* __restrict__ rowptr, const unsigned* __restrict__ boff) {
    int gid = blockIdx.x * SCAN_BLK + threadIdx.x;
    if (gid < N_NODES) rowptr[gid] += (int)boff[blockIdx.x];
    if (gid == 0) rowptr[N_NODES] = N_EDGES;
}

// ---------------- region-pinned scatter (esrc window + cur both L2-local) ----------------
__global__ __launch_bounds__(256) void k_scatter_reg(const unsigned long long* __restrict__ bpack,
                                                     const int* __restrict__ runbase,
                                                     const int* __restrict__ rowptr,
                                                     unsigned* __restrict__ cur,
                                                     int* __restrict__ esrc) {
    int r = blockIdx.x & (NREG - 1);
    int bi = blockIdx.x >> 3;
    int lo = runbase[r], hi = runbase[r + 1];
    for (int i = lo + bi * 256 + threadIdx.x; i < hi; i += REGBLK * 256) {
        unsigned long long p = bpack[i];
        int d = (int)(p >> 32);
        int s = (int)(unsigned)p;
        int slot = rowptr[d] + (int)atomicAdd(&cur[d], 1u);
        esrc[slot] = s;
    }
}

// ---------------- mean aggregation ----------------
// one wave per node; 16 lanes x short8 (16B) cover a 256B feature row;
// 4 edges in flight per wave-iteration; cross-group reduce via shfl_xor.
__global__ void k_aggregate(const unsigned short* __restrict__ feat,
                            const int* __restrict__ esrc,
                            const int* __restrict__ rowptr,
                            unsigned short* __restrict__ out) {
    int node = blockIdx.x * 4 + (threadIdx.x >> 6);
    if (node >= N_NODES) return;
    int lane = threadIdx.x & 63;
    int sub = lane >> 4;          // which of 4 concurrent edges
    int fl = lane & 15;           // feature lane: feats [fl*8, fl*8+8)
    int s = rowptr[node], e = rowptr[node + 1];
    float acc[8];
#pragma unroll
    for (int q = 0; q < 8; ++q) acc[q] = 0.f;

    for (int j = s + sub; j < e; j += 4) {
        int sv = esrc[j];
        short8 v = *(const short8*)(feat + (size_t)sv * FDIM + fl * 8);
#pragma unroll
        for (int q = 0; q < 8; ++q) acc[q] += bf2f((unsigned short)v[q]);
    }
#pragma unroll
    for (int q = 0; q < 8; ++q) {
        acc[q] += __shfl_xor(acc[q], 16, 64);
        acc[q] += __shfl_xor(acc[q], 32, 64);
    }
    int deg = e - s;
    float inv = 1.0f / (float)(deg > 1 ? deg : 1);
    if (sub == 0) {
        short8 o;
#pragma unroll
        for (int q = 0; q < 8; ++q) o[q] = (short)f2bf(acc[q] * inv);
        *(short8*)(out + (size_t)node * FDIM + fl * 8) = o;
    }
}

// ---------------- pack weights: Bp[col][k] = W[k][col], bf16; pad cols with 0 ----------------
__global__ void k_pack(const float* __restrict__ Wl, const float* __restrict__ Wr,
                       const float* __restrict__ bin, unsigned short* __restrict__ Bp,
                       float* __restrict__ bout, int ncols_out, int ncols_src, int Keach) {
    int K = (Wr != nullptr) ? 2 * Keach : Keach;
    int idx = blockIdx.x * blockDim.x + threadIdx.x;
    if (idx >= ncols_out * K) return;
    int col = idx / K, k = idx % K;
    float v = 0.f;
    if (col < ncols_src)
        v = (k < Keach) ? Wl[(size_t)k * ncols_src + col]
                        : Wr[(size_t)(k - Keach) * ncols_src + col];
    Bp[(size_t)col * K + k] = f2bf(v);
    if (k == 0) bout[col] = (col < ncols_src) ? bin[col] : 0.f;
}

// ---------------- fused layer GEMM: out = relu([A0 | A1] @ Bp^T + bias), bf16 out ----------------
__global__ __launch_bounds__(256) void k_gemm_layer(
        const unsigned short* __restrict__ A0, const unsigned short* __restrict__ A1,
        const unsigned short* __restrict__ Bp, const float* __restrict__ bias,
        unsigned short* __restrict__ out) {
    int wave = threadIdx.x >> 6;
    int lane = threadIdx.x & 63;
    int rowblk = blockIdx.x * 64 + wave * 16;
    int lrow = lane & 15;
    int kgrp = lane >> 4;
    int arow = rowblk + lrow; if (arow > N_NODES - 1) arow = N_NODES - 1;

    f32x4 acc[8];
#pragma unroll
    for (int c = 0; c < 8; ++c) acc[c] = (f32x4){0.f, 0.f, 0.f, 0.f};

#pragma unroll
    for (int kb = 0; kb < 8; ++kb) {
        const unsigned short* Asrc = (kb < 4) ? A0 : A1;
        int kk = (kb & 3) * 32 + kgrp * 8;
        short8 a = *(const short8*)(Asrc + (size_t)arow * FDIM + kk);
        int kB = kb * 32 + kgrp * 8;
#pragma unroll
        for (int c = 0; c < 8; ++c) {
            short8 b = *(const short8*)(Bp + (size_t)(c * 16 + lrow) * 256 + kB);
            acc[c] = __builtin_amdgcn_mfma_f32_16x16x32_bf16(a, b, acc[c], 0, 0, 0);
        }
    }

    int orowbase = rowblk + kgrp * 4;
#pragma unroll
    for (int c = 0; c < 8; ++c) {
        int col = c * 16 + lrow;
        float bv = bias[col];
#pragma unroll
        for (int i = 0; i < 4; ++i) {
            int r = orowbase + i;
            if (r < N_NODES) {
                float v = acc[c][i] + bv;
                v = fmaxf(v, 0.f);
                out[(size_t)r * FDIM + col] = f2bf(v);
            }
        }
    }
}

// ---------------- output GEMM: out = A0 @ Bp^T + bias, fp32 out [N][40], K = 128 ----------------
__global__ __launch_bounds__(256) void k_gemm_out(
        const unsigned short* __restrict__ A0, const unsigned short* __restrict__ Bp,
        const float* __restrict__ bias, float* __restrict__ out) {
    int wave = threadIdx.x >> 6;
    int lane = threadIdx.x & 63;
    int rowblk = blockIdx.x * 64 + wave * 16;
    int lrow = lane & 15;
    int kgrp = lane >> 4;
    int arow = rowblk + lrow; if (arow > N_NODES - 1) arow = N_NODES - 1;

    f32x4 acc[3];
#pragma unroll
    for (int c = 0; c < 3; ++c) acc[c] = (f32x4){0.f, 0.f, 0.f, 0.f};

#pragma unroll
    for (int kb = 0; kb < 4; ++kb) {
        int kk = kb * 32 + kgrp * 8;
        short8 a = *(const short8*)(A0 + (size_t)arow * FDIM + kk);
#pragma unroll
        for (int c = 0; c < 3; ++c) {
            short8 b = *(const short8*)(Bp + (size_t)(c * 16 + lrow) * FDIM + kk);
            acc[c] = __builtin_amdgcn_mfma_f32_16x16x32_bf16(a, b, acc[c], 0, 0, 0);
        }
    }

    int orowbase = rowblk + kgrp * 4;
#pragma unroll
    for (int c = 0; c < 3; ++c) {
        int col = c * 16 + lrow;
        if (col < NCLS) {
            float bv = bias[col];
#pragma unroll
            for (int i = 0; i < 4; ++i) {
                int r = orowbase + i;
                if (r < N_NODES)
                    out[(size_t)r * NCLS + col] = acc[c][i] + bv;
            }
        }
    }
}

extern "C" void kernel_launch(void* const* d_in, const int* in_sizes, int n_in,
                              void* d_out, int out_size, void* d_ws, size_t ws_size,
                              hipStream_t stream) {
    const float* x    = (const float*)d_in[0];
    const int*   ei   = (const int*)d_in[1];
    const float* W1l  = (const float*)d_in[2];
    const float* W1r  = (const float*)d_in[3];
    const float* b1   = (const float*)d_in[4];
    const float* W2l  = (const float*)d_in[5];
    const float* W2r  = (const float*)d_in[6];
    const float* b2   = (const float*)d_in[7];
    const float* Wout = (const float*)d_in[8];
    const float* bout = (const float*)d_in[9];
    const int* src = ei;
    const int* dst = ei + N_EDGES;

    char* ws = (char*)d_ws;
    size_t off = 0;
    auto alloc = [&](size_t bytes) -> void* {
        void* p = ws + off;
        off += (bytes + 255) & ~(size_t)255;
        return p;
    };
    unsigned short* xb   = (unsigned short*)alloc((size_t)N_NODES * FDIM * 2);
    unsigned short* aggn = (unsigned short*)alloc((size_t)N_NODES * FDIM * 2);
    unsigned short* h1   = (unsigned short*)alloc((size_t)N_NODES * FDIM * 2);
    unsigned short* h2   = (unsigned short*)alloc((size_t)N_NODES * FDIM * 2);
    unsigned short* Bp1  = (unsigned short*)alloc((size_t)FDIM * 256 * 2);
    unsigned short* Bp2  = (unsigned short*)alloc((size_t)FDIM * 256 * 2);
    unsigned short* Bp3  = (unsigned short*)alloc((size_t)NCLS_PAD * FDIM * 2);
    float* b1p = (float*)alloc(FDIM * 4);
    float* b2p = (float*)alloc(FDIM * 4);
    float* b3p = (float*)alloc(NCLS_PAD * 4);
    unsigned* cnt  = (unsigned*)alloc((size_t)N_NODES * 4);
    unsigned* cur  = (unsigned*)alloc((size_t)N_NODES * 4);
    int* rowptr    = (int*)alloc((size_t)(N_NODES + 1) * 4);
    int* esrc      = (int*)alloc((size_t)N_EDGES * 4);
    unsigned* bsum = (unsigned*)alloc((size_t)SCAN_NB * 4);
    unsigned* boff = (unsigned*)alloc((size_t)SCAN_NB * 4);
    int* bh        = (int*)alloc((size_t)NBLKA * NREG * 4);
    int* obh       = (int*)alloc((size_t)NBLKA * NREG * 4);
    int* runbase   = (int*)alloc((size_t)(NREG + 1) * 4);
    unsigned long long* bpack = (unsigned long long*)alloc((size_t)N_EDGES * 8);

    hipMemsetAsync(cnt, 0, (size_t)N_NODES * 4, stream);
    hipMemsetAsync(cur, 0, (size_t)N_NODES * 4, stream);

    // bf16 copy of x
    int n4 = N_NODES * FDIM / 4;
    k_cvt_bf16<<<(n4 + 255) / 256, 256, 0, stream>>>((const float4*)x, (ushort4*)xb, n4);

    // weight packs
    k_pack<<<(FDIM * 256 + 255) / 256, 256, 0, stream>>>(W1l, W1r, b1, Bp1, b1p, FDIM, FDIM, FDIM);
    k_pack<<<(FDIM * 256 + 255) / 256, 256, 0, stream>>>(W2l, W2r, b2, Bp2, b2p, FDIM, FDIM, FDIM);
    k_pack<<<(NCLS_PAD * FDIM + 255) / 256, 256, 0, stream>>>(Wout, nullptr, bout, Bp3, b3p, NCLS_PAD, NCLS, FDIM);

    // CSR build via contention-free radix partition
    k_countA<<<NBLKA, 256, 0, stream>>>(dst, bh);
    k_scanA<<<1, 1024, 0, stream>>>(bh, obh, runbase);
    k_binwrite<<<NBLKA, 256, 0, stream>>>(src, dst, obh, bpack);
    k_hist_reg<<<NREG * REGBLK, 256, 0, stream>>>(bpack, runbase, cnt);
    k_scan_local<<<SCAN_NB, SCAN_BLK, 0, stream>>>(cnt, rowptr, bsum);
    k_scan_bsum<<<1, 128, 0, stream>>>(bsum, boff);
    k_scan_add<<<SCAN_NB, SCAN_BLK, 0, stream>>>(rowptr, boff);
    k_scatter_reg<<<NREG * REGBLK, 256, 0, stream>>>(bpack, runbase, rowptr, cur, esrc);

    int aggGrid = (N_NODES + 3) / 4;
    int gemmGrid = (N_NODES + 63) / 64;

    // layer 1
    k_aggregate<<<aggGrid, 256, 0, stream>>>(xb, esrc, rowptr, aggn);
    k_gemm_layer<<<gemmGrid, 256, 0, stream>>>(aggn, xb, Bp1, b1p, h1);
    // layer 2
    k_aggregate<<<aggGrid, 256, 0, stream>>>(h1, esrc, rowptr, aggn);
    k_gemm_layer<<<gemmGrid, 256, 0, stream>>>(aggn, h1, Bp2, b2p, h2);
    // head
    k_gemm_out<<<gemmGrid, 256, 0, stream>>>(h2, Bp3, b3p, (float*)d_out);
}

// Round 6
// 397.442 us; speedup vs baseline: 1.1839x; 1.1839x over previous
//
#include <hip/hip_runtime.h>
#include <hip/hip_bf16.h>

#define N_NODES 100000
#define N_EDGES 1600000
#define FDIM 128
#define NCLS 40
#define NCLS_PAD 48

#define SCAN_BLK 1024
#define SCAN_NB ((N_NODES + SCAN_BLK - 1) / SCAN_BLK)   // 98

#define NREG 8
#define REG_SZ (N_NODES / NREG)                         // 12500 nodes per region
#define CHUNKA 4096
#define NBLKA ((N_EDGES + CHUNKA - 1) / CHUNKA)         // 391 partition blocks
#define REGBLK 64                                       // blocks per region for reg-pinned kernels

typedef __attribute__((ext_vector_type(8))) short short8;
typedef __attribute__((ext_vector_type(4))) float f32x4;

__device__ __forceinline__ float bf2f(unsigned short u) {
    union { unsigned int i; float f; } v; v.i = ((unsigned int)u) << 16; return v.f;
}
__device__ __forceinline__ unsigned short f2bf(float f) {
    __hip_bfloat16 h = __float2bfloat16(f);
    return *reinterpret_cast<unsigned short*>(&h);
}

// ---------------- fp32 -> bf16 bulk convert (vectorized) ----------------
__global__ void k_cvt_bf16(const float4* __restrict__ in, ushort4* __restrict__ out, int n4) {
    int i = blockIdx.x * blockDim.x + threadIdx.x;
    if (i >= n4) return;
    float4 v = in[i];
    ushort4 o;
    o.x = f2bf(v.x); o.y = f2bf(v.y); o.z = f2bf(v.z); o.w = f2bf(v.w);
    out[i] = o;
}

// ---------------- radix phase 1: per-block per-region counts (no global atomics) ----------------
__global__ __launch_bounds__(256) void k_countA(const int* __restrict__ dst, int* __restrict__ bh) {
    __shared__ unsigned h[NREG];
    if (threadIdx.x < NREG) h[threadIdx.x] = 0u;
    __syncthreads();
    int base = blockIdx.x * CHUNKA;
    int end = base + CHUNKA; if (end > N_EDGES) end = N_EDGES;
    for (int e = base + threadIdx.x; e < end; e += 256)
        atomicAdd(&h[dst[e] / REG_SZ], 1u);
    __syncthreads();
    if (threadIdx.x < NREG) bh[blockIdx.x * NREG + threadIdx.x] = (int)h[threadIdx.x];
}

// ---------------- radix phase 2: scan of bh in bin-major order -> private segments ----------------
__global__ __launch_bounds__(1024) void k_scanA(const int* __restrict__ bh,
                                                int* __restrict__ obh, int* __restrict__ runbase) {
    __shared__ unsigned lds[1024];
    const int TOT = NBLKA * NREG;            // 3128
    const int SEG = (TOT + 1023) / 1024;     // 4
    int t = threadIdx.x;
    int lo = t * SEG;
    int hi = lo + SEG; if (hi > TOT) hi = TOT;
    unsigned s = 0;
    for (int i = lo; i < hi; ++i) { int r = i / NBLKA, b = i % NBLKA; s += (unsigned)bh[b * NREG + r]; }
    lds[t] = s;
    __syncthreads();
    for (int d = 1; d < 1024; d <<= 1) {
        unsigned add = (t >= d) ? lds[t - d] : 0u;
        __syncthreads();
        lds[t] += add;
        __syncthreads();
    }
    unsigned run = (t == 0) ? 0u : lds[t - 1];
    for (int i = lo; i < hi; ++i) {
        int r = i / NBLKA, b = i % NBLKA;
        obh[b * NREG + r] = (int)run;
        if (b == 0) runbase[r] = (int)run;
        run += (unsigned)bh[b * NREG + r];
    }
    if (t == 1023) runbase[NREG] = N_EDGES;
}

// ---------------- radix phase 3: write packed (dst,src) into private segments ----------------
__global__ __launch_bounds__(256) void k_binwrite(const int* __restrict__ src, const int* __restrict__ dst,
                                                  const int* __restrict__ obh,
                                                  unsigned long long* __restrict__ bpack) {
    __shared__ unsigned pos[NREG];
    if (threadIdx.x < NREG) pos[threadIdx.x] = (unsigned)obh[blockIdx.x * NREG + threadIdx.x];
    __syncthreads();
    int base = blockIdx.x * CHUNKA;
    int end = base + CHUNKA; if (end > N_EDGES) end = N_EDGES;
    for (int e = base + threadIdx.x; e < end; e += 256) {
        int d = dst[e];
        int r = d / REG_SZ;
        unsigned p = atomicAdd(&pos[r], 1u);
        bpack[p] = ((unsigned long long)(unsigned)d << 32) | (unsigned)src[e];
    }
}

// ---------------- region-pinned degree histogram (XCD-local atomics) ----------------
__global__ __launch_bounds__(256) void k_hist_reg(const unsigned long long* __restrict__ bpack,
                                                  const int* __restrict__ runbase,
                                                  unsigned* __restrict__ cnt) {
    int r = blockIdx.x & (NREG - 1);
    int bi = blockIdx.x >> 3;
    int lo = runbase[r], hi = runbase[r + 1];
    for (int i = lo + bi * 256 + threadIdx.x; i < hi; i += REGBLK * 256)
        atomicAdd(&cnt[(int)(bpack[i] >> 32)], 1u);
}

// ---------------- hierarchical exclusive scan ----------------
__global__ __launch_bounds__(SCAN_BLK) void k_scan_local(
        const unsigned* __restrict__ cnt, int* __restrict__ rowptr,
        unsigned* __restrict__ bsum) {
    __shared__ unsigned lds[SCAN_BLK];
    int t = threadIdx.x;
    int gid = blockIdx.x * SCAN_BLK + t;
    unsigned v = (gid < N_NODES) ? cnt[gid] : 0u;
    lds[t] = v;
    __syncthreads();
    for (int d = 1; d < SCAN_BLK; d <<= 1) {
        unsigned add = (t >= d) ? lds[t - d] : 0u;
        __syncthreads();
        lds[t] += add;
        __syncthreads();
    }
    if (gid < N_NODES) rowptr[gid] = (int)(lds[t] - v);   // exclusive within block
    if (t == SCAN_BLK - 1) bsum[blockIdx.x] = lds[t];
}

__global__ void k_scan_bsum(const unsigned* __restrict__ bsum, unsigned* __restrict__ boff) {
    __shared__ unsigned lds[128];
    int t = threadIdx.x;
    unsigned v = (t < SCAN_NB) ? bsum[t] : 0u;
    lds[t] = v;
    __syncthreads();
    for (int d = 1; d < 128; d <<= 1) {
        unsigned add = (t >= d) ? lds[t - d] : 0u;
        __syncthreads();
        lds[t] += add;
        __syncthreads();
    }
    if (t < SCAN_NB) boff[t] = lds[t] - v;
}

__global__ __launch_bounds__(SCAN_BLK) void k_scan_add(
        int* __restrict__ rowptr, const unsigned* __restrict__ boff) {
    int gid = blockIdx.x * SCAN_BLK + threadIdx.x;
    if (gid < N_NODES) rowptr[gid] += (int)boff[blockIdx.x];
    if (gid == 0) rowptr[N_NODES] = N_EDGES;
}

// ---------------- region-pinned scatter (esrc window + cur both L2-local) ----------------
__global__ __launch_bounds__(256) void k_scatter_reg(const unsigned long long* __restrict__ bpack,
                                                     const int* __restrict__ runbase,
                                                     const int* __restrict__ rowptr,
                                                     unsigned* __restrict__ cur,
                                                     int* __restrict__ esrc) {
    int r = blockIdx.x & (NREG - 1);
    int bi = blockIdx.x >> 3;
    int lo = runbase[r], hi = runbase[r + 1];
    for (int i = lo + bi * 256 + threadIdx.x; i < hi; i += REGBLK * 256) {
        unsigned long long p = bpack[i];
        int d = (int)(p >> 32);
        int s = (int)(unsigned)p;
        int slot = rowptr[d] + (int)atomicAdd(&cur[d], 1u);
        esrc[slot] = s;
    }
}

// ---------------- mean aggregation ----------------
__global__ void k_aggregate(const unsigned short* __restrict__ feat,
                            const int* __restrict__ esrc,
                            const int* __restrict__ rowptr,
                            unsigned short* __restrict__ out) {
    int node = blockIdx.x * 4 + (threadIdx.x >> 6);
    if (node >= N_NODES) return;
    int lane = threadIdx.x & 63;
    int sub = lane >> 4;          // which of 4 concurrent edges
    int fl = lane & 15;           // feature lane: feats [fl*8, fl*8+8)
    int s = rowptr[node], e = rowptr[node + 1];
    float acc[8];
#pragma unroll
    for (int q = 0; q < 8; ++q) acc[q] = 0.f;

    for (int j = s + sub; j < e; j += 4) {
        int sv = esrc[j];
        short8 v = *(const short8*)(feat + (size_t)sv * FDIM + fl * 8);
#pragma unroll
        for (int q = 0; q < 8; ++q) acc[q] += bf2f((unsigned short)v[q]);
    }
#pragma unroll
    for (int q = 0; q < 8; ++q) {
        acc[q] += __shfl_xor(acc[q], 16, 64);
        acc[q] += __shfl_xor(acc[q], 32, 64);
    }
    int deg = e - s;
    float inv = 1.0f / (float)(deg > 1 ? deg : 1);
    if (sub == 0) {
        short8 o;
#pragma unroll
        for (int q = 0; q < 8; ++q) o[q] = (short)f2bf(acc[q] * inv);
        *(short8*)(out + (size_t)node * FDIM + fl * 8) = o;
    }
}

// ---------------- pack weights, k-major fragments ----------------
// Bp[k8][col][8]: 8 consecutive k-elements for (col, k8) stored contiguously;
// consecutive cols at same k8 are adjacent -> B-frag loads (lanes 0..15 =
// consecutive cols) are fully coalesced 16B x 16 lanes.
__global__ void k_pack(const float* __restrict__ Wl, const float* __restrict__ Wr,
                       const float* __restrict__ bin, unsigned short* __restrict__ Bp,
                       float* __restrict__ bout, int ncols_out, int ncols_src, int Keach) {
    int K = (Wr != nullptr) ? 2 * Keach : Keach;
    int idx = blockIdx.x * blockDim.x + threadIdx.x;
    if (idx >= ncols_out * K) return;
    int col = idx / K, k = idx % K;
    float v = 0.f;
    if (col < ncols_src)
        v = (k < Keach) ? Wl[(size_t)k * ncols_src + col]
                        : Wr[(size_t)(k - Keach) * ncols_src + col];
    Bp[((size_t)(k >> 3) * ncols_out + col) * 8 + (k & 7)] = f2bf(v);
    if (k == 0) bout[col] = (col < ncols_src) ? bin[col] : 0.f;
}

// ---------------- fused layer GEMM: out = relu([A0 | A1] @ W + bias), bf16 out ----------------
// Bp layout: [k8=32][col=128][8] bf16.
__global__ __launch_bounds__(256) void k_gemm_layer(
        const unsigned short* __restrict__ A0, const unsigned short* __restrict__ A1,
        const unsigned short* __restrict__ Bp, const float* __restrict__ bias,
        unsigned short* __restrict__ out) {
    int wave = threadIdx.x >> 6;
    int lane = threadIdx.x & 63;
    int rowblk = blockIdx.x * 64 + wave * 16;
    int lrow = lane & 15;
    int kgrp = lane >> 4;
    int arow = rowblk + lrow; if (arow > N_NODES - 1) arow = N_NODES - 1;

    f32x4 acc[8];
#pragma unroll
    for (int c = 0; c < 8; ++c) acc[c] = (f32x4){0.f, 0.f, 0.f, 0.f};

#pragma unroll
    for (int kb = 0; kb < 8; ++kb) {
        const unsigned short* Asrc = (kb < 4) ? A0 : A1;
        int kk = (kb & 3) * 32 + kgrp * 8;
        short8 a = *(const short8*)(Asrc + (size_t)arow * FDIM + kk);
        int k8 = kb * 4 + kgrp;
        const unsigned short* brow = Bp + ((size_t)k8 * FDIM + lrow) * 8;
#pragma unroll
        for (int c = 0; c < 8; ++c) {
            short8 b = *(const short8*)(brow + c * 16 * 8);
            acc[c] = __builtin_amdgcn_mfma_f32_16x16x32_bf16(a, b, acc[c], 0, 0, 0);
        }
    }

    int orowbase = rowblk + kgrp * 4;
#pragma unroll
    for (int c = 0; c < 8; ++c) {
        int col = c * 16 + lrow;
        float bv = bias[col];
#pragma unroll
        for (int i = 0; i < 4; ++i) {
            int r = orowbase + i;
            if (r < N_NODES) {
                float v = acc[c][i] + bv;
                v = fmaxf(v, 0.f);
                out[(size_t)r * FDIM + col] = f2bf(v);
            }
        }
    }
}

// ---------------- output GEMM: out = A0 @ W + bias, fp32 out [N][40] ----------------
// Bp layout: [k8=16][col=48][8] bf16.
__global__ __launch_bounds__(256) void k_gemm_out(
        const unsigned short* __restrict__ A0, const unsigned short* __restrict__ Bp,
        const float* __restrict__ bias, float* __restrict__ out) {
    int wave = threadIdx.x >> 6;
    int lane = threadIdx.x & 63;
    int rowblk = blockIdx.x * 64 + wave * 16;
    int lrow = lane & 15;
    int kgrp = lane >> 4;
    int arow = rowblk + lrow; if (arow > N_NODES - 1) arow = N_NODES - 1;

    f32x4 acc[3];
#pragma unroll
    for (int c = 0; c < 3; ++c) acc[c] = (f32x4){0.f, 0.f, 0.f, 0.f};

#pragma unroll
    for (int kb = 0; kb < 4; ++kb) {
        int kk = kb * 32 + kgrp * 8;
        short8 a = *(const short8*)(A0 + (size_t)arow * FDIM + kk);
        int k8 = kb * 4 + kgrp;
        const unsigned short* brow = Bp + ((size_t)k8 * NCLS_PAD + lrow) * 8;
#pragma unroll
        for (int c = 0; c < 3; ++c) {
            short8 b = *(const short8*)(brow + c * 16 * 8);
            acc[c] = __builtin_amdgcn_mfma_f32_16x16x32_bf16(a, b, acc[c], 0, 0, 0);
        }
    }

    int orowbase = rowblk + kgrp * 4;
#pragma unroll
    for (int c = 0; c < 3; ++c) {
        int col = c * 16 + lrow;
        if (col < NCLS) {
            float bv = bias[col];
#pragma unroll
            for (int i = 0; i < 4; ++i) {
                int r = orowbase + i;
                if (r < N_NODES)
                    out[(size_t)r * NCLS + col] = acc[c][i] + bv;
            }
        }
    }
}

extern "C" void kernel_launch(void* const* d_in, const int* in_sizes, int n_in,
                              void* d_out, int out_size, void* d_ws, size_t ws_size,
                              hipStream_t stream) {
    const float* x    = (const float*)d_in[0];
    const int*   ei   = (const int*)d_in[1];
    const float* W1l  = (const float*)d_in[2];
    const float* W1r  = (const float*)d_in[3];
    const float* b1   = (const float*)d_in[4];
    const float* W2l  = (const float*)d_in[5];
    const float* W2r  = (const float*)d_in[6];
    const float* b2   = (const float*)d_in[7];
    const float* Wout = (const float*)d_in[8];
    const float* bout = (const float*)d_in[9];
    const int* src = ei;
    const int* dst = ei + N_EDGES;

    char* ws = (char*)d_ws;
    size_t off = 0;
    auto alloc = [&](size_t bytes) -> void* {
        void* p = ws + off;
        off += (bytes + 255) & ~(size_t)255;
        return p;
    };
    unsigned short* xb   = (unsigned short*)alloc((size_t)N_NODES * FDIM * 2);
    unsigned short* aggn = (unsigned short*)alloc((size_t)N_NODES * FDIM * 2);
    unsigned short* h1   = (unsigned short*)alloc((size_t)N_NODES * FDIM * 2);
    unsigned short* h2   = (unsigned short*)alloc((size_t)N_NODES * FDIM * 2);
    unsigned short* Bp1  = (unsigned short*)alloc((size_t)FDIM * 256 * 2);
    unsigned short* Bp2  = (unsigned short*)alloc((size_t)FDIM * 256 * 2);
    unsigned short* Bp3  = (unsigned short*)alloc((size_t)NCLS_PAD * FDIM * 2);
    float* b1p = (float*)alloc(FDIM * 4);
    float* b2p = (float*)alloc(FDIM * 4);
    float* b3p = (float*)alloc(NCLS_PAD * 4);
    unsigned* cnt  = (unsigned*)alloc((size_t)N_NODES * 4);
    unsigned* cur  = (unsigned*)alloc((size_t)N_NODES * 4);
    int* rowptr    = (int*)alloc((size_t)(N_NODES + 1) * 4);
    int* esrc      = (int*)alloc((size_t)N_EDGES * 4);
    unsigned* bsum = (unsigned*)alloc((size_t)SCAN_NB * 4);
    unsigned* boff = (unsigned*)alloc((size_t)SCAN_NB * 4);
    int* bh        = (int*)alloc((size_t)NBLKA * NREG * 4);
    int* obh       = (int*)alloc((size_t)NBLKA * NREG * 4);
    int* runbase   = (int*)alloc((size_t)(NREG + 1) * 4);
    unsigned long long* bpack = (unsigned long long*)alloc((size_t)N_EDGES * 8);

    hipMemsetAsync(cnt, 0, (size_t)N_NODES * 4, stream);
    hipMemsetAsync(cur, 0, (size_t)N_NODES * 4, stream);

    // bf16 copy of x
    int n4 = N_NODES * FDIM / 4;
    k_cvt_bf16<<<(n4 + 255) / 256, 256, 0, stream>>>((const float4*)x, (ushort4*)xb, n4);

    // weight packs (k-major fragment layout)
    k_pack<<<(FDIM * 256 + 255) / 256, 256, 0, stream>>>(W1l, W1r, b1, Bp1, b1p, FDIM, FDIM, FDIM);
    k_pack<<<(FDIM * 256 + 255) / 256, 256, 0, stream>>>(W2l, W2r, b2, Bp2, b2p, FDIM, FDIM, FDIM);
    k_pack<<<(NCLS_PAD * FDIM + 255) / 256, 256, 0, stream>>>(Wout, nullptr, bout, Bp3, b3p, NCLS_PAD, NCLS, FDIM);

    // CSR build via contention-free radix partition
    k_countA<<<NBLKA, 256, 0, stream>>>(dst, bh);
    k_scanA<<<1, 1024, 0, stream>>>(bh, obh, runbase);
    k_binwrite<<<NBLKA, 256, 0, stream>>>(src, dst, obh, bpack);
    k_hist_reg<<<NREG * REGBLK, 256, 0, stream>>>(bpack, runbase, cnt);
    k_scan_local<<<SCAN_NB, SCAN_BLK, 0, stream>>>(cnt, rowptr, bsum);
    k_scan_bsum<<<1, 128, 0, stream>>>(bsum, boff);
    k_scan_add<<<SCAN_NB, SCAN_BLK, 0, stream>>>(rowptr, boff);
    k_scatter_reg<<<NREG * REGBLK, 256, 0, stream>>>(bpack, runbase, rowptr, cur, esrc);

    int aggGrid = (N_NODES + 3) / 4;
    int gemmGrid = (N_NODES + 63) / 64;

    // layer 1
    k_aggregate<<<aggGrid, 256, 0, stream>>>(xb, esrc, rowptr, aggn);
    k_gemm_layer<<<gemmGrid, 256, 0, stream>>>(aggn, xb, Bp1, b1p, h1);
    // layer 2
    k_aggregate<<<aggGrid, 256, 0, stream>>>(h1, esrc, rowptr, aggn);
    k_gemm_layer<<<gemmGrid, 256, 0, stream>>>(aggn, h1, Bp2, b2p, h2);
    // head
    k_gemm_out<<<gemmGrid, 256, 0, stream>>>(h2, Bp3, b3p, (float*)d_out);
}

// Round 7
// 365.549 us; speedup vs baseline: 1.2872x; 1.0872x over previous
//
#include <hip/hip_runtime.h>
#include <hip/hip_bf16.h>

#define N_NODES 100000
#define N_EDGES 1600000
#define FDIM 128
#define NCLS 40
#define NCLS_PAD 48

#define NBINS ((N_NODES + 255) / 256)        // 391 buckets of 256 nodes
#define NBLKB 128                            // partition blocks
#define CHUNKB (N_EDGES / NBLKB)             // 12500 edges per block
#define SCANTOT (NBINS * NBLKB)              // 50048
#define SCANSEG ((SCANTOT + 1023) / 1024)    // 49

typedef __attribute__((ext_vector_type(8))) short short8;
typedef __attribute__((ext_vector_type(4))) float f32x4;

__device__ __forceinline__ float bf2f(unsigned short u) {
    union { unsigned int i; float f; } v; v.i = ((unsigned int)u) << 16; return v.f;
}
__device__ __forceinline__ unsigned short f2bf(float f) {
    __hip_bfloat16 h = __float2bfloat16(f);
    return *reinterpret_cast<unsigned short*>(&h);
}

// ---------------- fp32 -> bf16 bulk convert (vectorized) ----------------
__global__ void k_cvt_bf16(const float4* __restrict__ in, ushort4* __restrict__ out, int n4) {
    int i = blockIdx.x * blockDim.x + threadIdx.x;
    if (i >= n4) return;
    float4 v = in[i];
    ushort4 o;
    o.x = f2bf(v.x); o.y = f2bf(v.y); o.z = f2bf(v.z); o.w = f2bf(v.w);
    out[i] = o;
}

// ---------------- radix phase 1: per-block 391-bucket counts (LDS only) ----------------
__global__ __launch_bounds__(256) void k_countB(const int* __restrict__ dst, int* __restrict__ bh) {
    __shared__ unsigned h[NBINS];
    for (int r = threadIdx.x; r < NBINS; r += 256) h[r] = 0u;
    __syncthreads();
    int base = blockIdx.x * CHUNKB;
    int end = base + CHUNKB; if (end > N_EDGES) end = N_EDGES;
    for (int e = base + threadIdx.x; e < end; e += 256)
        atomicAdd(&h[dst[e] >> 8], 1u);
    __syncthreads();
    for (int r = threadIdx.x; r < NBINS; r += 256)
        bh[blockIdx.x * NBINS + r] = (int)h[r];
}

// ---------------- radix phase 2: scan 50K counts bucket-major -> segments + bucket bases ----------------
__global__ __launch_bounds__(1024) void k_scanB(const int* __restrict__ bh,
                                                int* __restrict__ obh, int* __restrict__ bucketbase) {
    __shared__ unsigned lds[1024];
    int t = threadIdx.x;
    int lo = t * SCANSEG;
    int hi = lo + SCANSEG; if (hi > SCANTOT) hi = SCANTOT;
    unsigned s = 0;
    for (int g = lo; g < hi; ++g) { int r = g >> 7, b = g & (NBLKB - 1); s += (unsigned)bh[b * NBINS + r]; }
    lds[t] = s;
    __syncthreads();
    for (int d = 1; d < 1024; d <<= 1) {
        unsigned add = (t >= d) ? lds[t - d] : 0u;
        __syncthreads();
        lds[t] += add;
        __syncthreads();
    }
    unsigned run = (t == 0) ? 0u : lds[t - 1];
    for (int g = lo; g < hi; ++g) {
        int r = g >> 7, b = g & (NBLKB - 1);
        obh[b * NBINS + r] = (int)run;
        if (b == 0) bucketbase[r] = (int)run;
        run += (unsigned)bh[b * NBINS + r];
    }
    if (t == 1023) bucketbase[NBINS] = N_EDGES;
}

// ---------------- radix phase 3: scatter packed (dst,src) into private segments ----------------
__global__ __launch_bounds__(256) void k_binwriteB(const int* __restrict__ src, const int* __restrict__ dst,
                                                   const int* __restrict__ obh,
                                                   unsigned long long* __restrict__ bpack) {
    __shared__ unsigned pos[NBINS];
    for (int r = threadIdx.x; r < NBINS; r += 256)
        pos[r] = (unsigned)obh[blockIdx.x * NBINS + r];
    __syncthreads();
    int base = blockIdx.x * CHUNKB;
    int end = base + CHUNKB; if (end > N_EDGES) end = N_EDGES;
    for (int e = base + threadIdx.x; e < end; e += 256) {
        int d = dst[e];
        unsigned p = atomicAdd(&pos[d >> 8], 1u);
        bpack[p] = ((unsigned long long)(unsigned)d << 32) | (unsigned)src[e];
    }
}

// ---------------- radix phase 4: per-bucket in-LDS CSR (rowptr + esrc), no global atomics ----------------
__global__ __launch_bounds__(256) void k_bucket_csr(const unsigned long long* __restrict__ bpack,
                                                    const int* __restrict__ bucketbase,
                                                    int* __restrict__ rowptr,
                                                    int* __restrict__ esrc) {
    __shared__ unsigned c[256];
    int b = blockIdx.x;
    int t = threadIdx.x;
    int bb = bucketbase[b], be = bucketbase[b + 1];
    c[t] = 0u;
    __syncthreads();
    // pass 1: local degree histogram
    for (int i = bb + t; i < be; i += 256)
        atomicAdd(&c[(unsigned)(bpack[i] >> 32) & 255u], 1u);
    __syncthreads();
    unsigned own = c[t];
    // inclusive scan over 256 local degrees
    for (int d = 1; d < 256; d <<= 1) {
        unsigned add = (t >= d) ? c[t - d] : 0u;
        __syncthreads();
        c[t] += add;
        __syncthreads();
    }
    unsigned excl = c[t] - own;
    int node = (b << 8) + t;
    if (node < N_NODES) rowptr[node] = bb + (int)excl;
    if (b == NBINS - 1 && t == 0) rowptr[N_NODES] = N_EDGES;
    __syncthreads();
    c[t] = excl;               // reuse as position cursors
    __syncthreads();
    // pass 2: scatter srcs into the bucket's dense esrc window (~16KB, bursty)
    for (int i = bb + t; i < be; i += 256) {
        unsigned long long p = bpack[i];
        unsigned slot = atomicAdd(&c[(unsigned)(p >> 32) & 255u], 1u);
        esrc[bb + (int)slot] = (int)(unsigned)p;
    }
}

// ---------------- mean aggregation ----------------
__global__ void k_aggregate(const unsigned short* __restrict__ feat,
                            const int* __restrict__ esrc,
                            const int* __restrict__ rowptr,
                            unsigned short* __restrict__ out) {
    int node = blockIdx.x * 4 + (threadIdx.x >> 6);
    if (node >= N_NODES) return;
    int lane = threadIdx.x & 63;
    int sub = lane >> 4;          // which of 4 concurrent edges
    int fl = lane & 15;           // feature lane: feats [fl*8, fl*8+8)
    int s = rowptr[node], e = rowptr[node + 1];
    float acc[8];
#pragma unroll
    for (int q = 0; q < 8; ++q) acc[q] = 0.f;

    for (int j = s + sub; j < e; j += 4) {
        int sv = esrc[j];
        short8 v = *(const short8*)(feat + (size_t)sv * FDIM + fl * 8);
#pragma unroll
        for (int q = 0; q < 8; ++q) acc[q] += bf2f((unsigned short)v[q]);
    }
#pragma unroll
    for (int q = 0; q < 8; ++q) {
        acc[q] += __shfl_xor(acc[q], 16, 64);
        acc[q] += __shfl_xor(acc[q], 32, 64);
    }
    int deg = e - s;
    float inv = 1.0f / (float)(deg > 1 ? deg : 1);
    if (sub == 0) {
        short8 o;
#pragma unroll
        for (int q = 0; q < 8; ++q) o[q] = (short)f2bf(acc[q] * inv);
        *(short8*)(out + (size_t)node * FDIM + fl * 8) = o;
    }
}

// ---------------- pack weights, k-major fragments ----------------
// Bp[k8][col][8]: B-frag loads (lanes 0..15 = consecutive cols) fully coalesced.
__global__ void k_pack(const float* __restrict__ Wl, const float* __restrict__ Wr,
                       const float* __restrict__ bin, unsigned short* __restrict__ Bp,
                       float* __restrict__ bout, int ncols_out, int ncols_src, int Keach) {
    int K = (Wr != nullptr) ? 2 * Keach : Keach;
    int idx = blockIdx.x * blockDim.x + threadIdx.x;
    if (idx >= ncols_out * K) return;
    int col = idx / K, k = idx % K;
    float v = 0.f;
    if (col < ncols_src)
        v = (k < Keach) ? Wl[(size_t)k * ncols_src + col]
                        : Wr[(size_t)(k - Keach) * ncols_src + col];
    Bp[((size_t)(k >> 3) * ncols_out + col) * 8 + (k & 7)] = f2bf(v);
    if (k == 0) bout[col] = (col < ncols_src) ? bin[col] : 0.f;
}

// ---------------- fused layer GEMM: out = relu([A0 | A1] @ W + bias), bf16 out ----------------
// Bp layout: [k8=32][col=128][8] bf16.
__global__ __launch_bounds__(256) void k_gemm_layer(
        const unsigned short* __restrict__ A0, const unsigned short* __restrict__ A1,
        const unsigned short* __restrict__ Bp, const float* __restrict__ bias,
        unsigned short* __restrict__ out) {
    int wave = threadIdx.x >> 6;
    int lane = threadIdx.x & 63;
    int rowblk = blockIdx.x * 64 + wave * 16;
    int lrow = lane & 15;
    int kgrp = lane >> 4;
    int arow = rowblk + lrow; if (arow > N_NODES - 1) arow = N_NODES - 1;

    f32x4 acc[8];
#pragma unroll
    for (int c = 0; c < 8; ++c) acc[c] = (f32x4){0.f, 0.f, 0.f, 0.f};

#pragma unroll
    for (int kb = 0; kb < 8; ++kb) {
        const unsigned short* Asrc = (kb < 4) ? A0 : A1;
        int kk = (kb & 3) * 32 + kgrp * 8;
        short8 a = *(const short8*)(Asrc + (size_t)arow * FDIM + kk);
        int k8 = kb * 4 + kgrp;
        const unsigned short* brow = Bp + ((size_t)k8 * FDIM + lrow) * 8;
#pragma unroll
        for (int c = 0; c < 8; ++c) {
            short8 b = *(const short8*)(brow + c * 16 * 8);
            acc[c] = __builtin_amdgcn_mfma_f32_16x16x32_bf16(a, b, acc[c], 0, 0, 0);
        }
    }

    int orowbase = rowblk + kgrp * 4;
#pragma unroll
    for (int c = 0; c < 8; ++c) {
        int col = c * 16 + lrow;
        float bv = bias[col];
#pragma unroll
        for (int i = 0; i < 4; ++i) {
            int r = orowbase + i;
            if (r < N_NODES) {
                float v = acc[c][i] + bv;
                v = fmaxf(v, 0.f);
                out[(size_t)r * FDIM + col] = f2bf(v);
            }
        }
    }
}

// ---------------- output GEMM: out = A0 @ W + bias, fp32 out [N][40] ----------------
// Bp layout: [k8=16][col=48][8] bf16.
__global__ __launch_bounds__(256) void k_gemm_out(
        const unsigned short* __restrict__ A0, const unsigned short* __restrict__ Bp,
        const float* __restrict__ bias, float* __restrict__ out) {
    int wave = threadIdx.x >> 6;
    int lane = threadIdx.x & 63;
    int rowblk = blockIdx.x * 64 + wave * 16;
    int lrow = lane & 15;
    int kgrp = lane >> 4;
    int arow = rowblk + lrow; if (arow > N_NODES - 1) arow = N_NODES - 1;

    f32x4 acc[3];
#pragma unroll
    for (int c = 0; c < 3; ++c) acc[c] = (f32x4){0.f, 0.f, 0.f, 0.f};

#pragma unroll
    for (int kb = 0; kb < 4; ++kb) {
        int kk = kb * 32 + kgrp * 8;
        short8 a = *(const short8*)(A0 + (size_t)arow * FDIM + kk);
        int k8 = kb * 4 + kgrp;
        const unsigned short* brow = Bp + ((size_t)k8 * NCLS_PAD + lrow) * 8;
#pragma unroll
        for (int c = 0; c < 3; ++c) {
            short8 b = *(const short8*)(brow + c * 16 * 8);
            acc[c] = __builtin_amdgcn_mfma_f32_16x16x32_bf16(a, b, acc[c], 0, 0, 0);
        }
    }

    int orowbase = rowblk + kgrp * 4;
#pragma unroll
    for (int c = 0; c < 3; ++c) {
        int col = c * 16 + lrow;
        if (col < NCLS) {
            float bv = bias[col];
#pragma unroll
            for (int i = 0; i < 4; ++i) {
                int r = orowbase + i;
                if (r < N_NODES)
                    out[(size_t)r * NCLS + col] = acc[c][i] + bv;
            }
        }
    }
}

extern "C" void kernel_launch(void* const* d_in, const int* in_sizes, int n_in,
                              void* d_out, int out_size, void* d_ws, size_t ws_size,
                              hipStream_t stream) {
    const float* x    = (const float*)d_in[0];
    const int*   ei   = (const int*)d_in[1];
    const float* W1l  = (const float*)d_in[2];
    const float* W1r  = (const float*)d_in[3];
    const float* b1   = (const float*)d_in[4];
    const float* W2l  = (const float*)d_in[5];
    const float* W2r  = (const float*)d_in[6];
    const float* b2   = (const float*)d_in[7];
    const float* Wout = (const float*)d_in[8];
    const float* bout = (const float*)d_in[9];
    const int* src = ei;
    const int* dst = ei + N_EDGES;

    char* ws = (char*)d_ws;
    size_t off = 0;
    auto alloc = [&](size_t bytes) -> void* {
        void* p = ws + off;
        off += (bytes + 255) & ~(size_t)255;
        return p;
    };
    unsigned short* xb   = (unsigned short*)alloc((size_t)N_NODES * FDIM * 2);
    unsigned short* aggn = (unsigned short*)alloc((size_t)N_NODES * FDIM * 2);
    unsigned short* h1   = (unsigned short*)alloc((size_t)N_NODES * FDIM * 2);
    unsigned short* h2   = (unsigned short*)alloc((size_t)N_NODES * FDIM * 2);
    unsigned short* Bp1  = (unsigned short*)alloc((size_t)FDIM * 256 * 2);
    unsigned short* Bp2  = (unsigned short*)alloc((size_t)FDIM * 256 * 2);
    unsigned short* Bp3  = (unsigned short*)alloc((size_t)NCLS_PAD * FDIM * 2);
    float* b1p = (float*)alloc(FDIM * 4);
    float* b2p = (float*)alloc(FDIM * 4);
    float* b3p = (float*)alloc(NCLS_PAD * 4);
    int* rowptr    = (int*)alloc((size_t)(N_NODES + 1) * 4);
    int* esrc      = (int*)alloc((size_t)N_EDGES * 4);
    int* bh        = (int*)alloc((size_t)NBLKB * NBINS * 4);
    int* obh       = (int*)alloc((size_t)NBLKB * NBINS * 4);
    int* bucketbase= (int*)alloc((size_t)(NBINS + 1) * 4);
    unsigned long long* bpack = (unsigned long long*)alloc((size_t)N_EDGES * 8);

    // bf16 copy of x
    int n4 = N_NODES * FDIM / 4;
    k_cvt_bf16<<<(n4 + 255) / 256, 256, 0, stream>>>((const float4*)x, (ushort4*)xb, n4);

    // weight packs (k-major fragment layout)
    k_pack<<<(FDIM * 256 + 255) / 256, 256, 0, stream>>>(W1l, W1r, b1, Bp1, b1p, FDIM, FDIM, FDIM);
    k_pack<<<(FDIM * 256 + 255) / 256, 256, 0, stream>>>(W2l, W2r, b2, Bp2, b2p, FDIM, FDIM, FDIM);
    k_pack<<<(NCLS_PAD * FDIM + 255) / 256, 256, 0, stream>>>(Wout, nullptr, bout, Bp3, b3p, NCLS_PAD, NCLS, FDIM);

    // CSR build: 391-bucket radix partition + per-bucket in-LDS finish
    k_countB<<<NBLKB, 256, 0, stream>>>(dst, bh);
    k_scanB<<<1, 1024, 0, stream>>>(bh, obh, bucketbase);
    k_binwriteB<<<NBLKB, 256, 0, stream>>>(src, dst, obh, bpack);
    k_bucket_csr<<<NBINS, 256, 0, stream>>>(bpack, bucketbase, rowptr, esrc);

    int aggGrid = (N_NODES + 3) / 4;
    int gemmGrid = (N_NODES + 63) / 64;

    // layer 1
    k_aggregate<<<aggGrid, 256, 0, stream>>>(xb, esrc, rowptr, aggn);
    k_gemm_layer<<<gemmGrid, 256, 0, stream>>>(aggn, xb, Bp1, b1p, h1);
    // layer 2
    k_aggregate<<<aggGrid, 256, 0, stream>>>(h1, esrc, rowptr, aggn);
    k_gemm_layer<<<gemmGrid, 256, 0, stream>>>(aggn, h1, Bp2, b2p, h2);
    // head
    k_gemm_out<<<gemmGrid, 256, 0, stream>>>(h2, Bp3, b3p, (float*)d_out);
}

// Round 8
// 293.068 us; speedup vs baseline: 1.6056x; 1.2473x over previous
//
#include <hip/hip_runtime.h>
#include <hip/hip_bf16.h>

#define N_NODES 100000
#define N_EDGES 1600000
#define FDIM 128
#define NCLS 40
#define NCLS_PAD 48

#define NBINS ((N_NODES + 255) / 256)        // 391 buckets of 256 nodes
#define NBLKB 128                            // partition blocks
#define CHUNKB (N_EDGES / NBLKB)             // 12500 edges per block
#define SCANTOT (NBINS * NBLKB)              // 50048
#define SCANB_NB ((SCANTOT + 1023) / 1024)   // 49

typedef __attribute__((ext_vector_type(8))) short short8;
typedef __attribute__((ext_vector_type(4))) float f32x4;

__device__ __forceinline__ float bf2f(unsigned short u) {
    union { unsigned int i; float f; } v; v.i = ((unsigned int)u) << 16; return v.f;
}
__device__ __forceinline__ unsigned short f2bf(float f) {
    __hip_bfloat16 h = __float2bfloat16(f);
    return *reinterpret_cast<unsigned short*>(&h);
}

// ---------------- fp32 -> bf16 bulk convert (vectorized) ----------------
__global__ void k_cvt_bf16(const float4* __restrict__ in, ushort4* __restrict__ out, int n4) {
    int i = blockIdx.x * blockDim.x + threadIdx.x;
    if (i >= n4) return;
    float4 v = in[i];
    ushort4 o;
    o.x = f2bf(v.x); o.y = f2bf(v.y); o.z = f2bf(v.z); o.w = f2bf(v.w);
    out[i] = o;
}

// ---------------- radix phase 1: per-block 391-bucket counts (LDS only) ----------------
__global__ __launch_bounds__(256) void k_countB(const int* __restrict__ dst, int* __restrict__ bh) {
    __shared__ unsigned h[NBINS];
    for (int r = threadIdx.x; r < NBINS; r += 256) h[r] = 0u;
    __syncthreads();
    int base = blockIdx.x * CHUNKB;
    int end = base + CHUNKB; if (end > N_EDGES) end = N_EDGES;
    for (int e = base + threadIdx.x; e < end; e += 256)
        atomicAdd(&h[dst[e] >> 8], 1u);
    __syncthreads();
    for (int r = threadIdx.x; r < NBINS; r += 256)
        bh[blockIdx.x * NBINS + r] = (int)h[r];
}

// ---------------- radix phase 2: hierarchical scan of 50K counts, bucket-major ----------------
// element g (bucket-major) maps to bh[b*NBINS+r], r = g>>7, b = g&127.
__global__ __launch_bounds__(1024) void k_scanB1(const int* __restrict__ bh,
                                                 int* __restrict__ obh,
                                                 unsigned* __restrict__ bsumB) {
    __shared__ unsigned lds[1024];
    int t = threadIdx.x;
    int g = blockIdx.x * 1024 + t;
    unsigned v = 0u;
    int r = g >> 7, b = g & (NBLKB - 1);
    if (g < SCANTOT) v = (unsigned)bh[b * NBINS + r];
    lds[t] = v;
    __syncthreads();
    for (int d = 1; d < 1024; d <<= 1) {
        unsigned add = (t >= d) ? lds[t - d] : 0u;
        __syncthreads();
        lds[t] += add;
        __syncthreads();
    }
    if (g < SCANTOT) obh[b * NBINS + r] = (int)(lds[t] - v);   // local exclusive
    if (t == 1023) bsumB[blockIdx.x] = lds[t];
}

__global__ void k_scanB2(const unsigned* __restrict__ bsumB, unsigned* __restrict__ boffB) {
    __shared__ unsigned lds[64];
    int t = threadIdx.x;
    unsigned v = (t < SCANB_NB) ? bsumB[t] : 0u;
    lds[t] = v;
    __syncthreads();
    for (int d = 1; d < 64; d <<= 1) {
        unsigned add = (t >= d) ? lds[t - d] : 0u;
        __syncthreads();
        lds[t] += add;
        __syncthreads();
    }
    if (t < SCANB_NB) boffB[t] = lds[t] - v;
}

__global__ __launch_bounds__(1024) void k_scanB3(int* __restrict__ obh,
                                                 const unsigned* __restrict__ boffB,
                                                 int* __restrict__ bucketbase) {
    int t = threadIdx.x;
    int g = blockIdx.x * 1024 + t;
    if (g < SCANTOT) {
        int r = g >> 7, b = g & (NBLKB - 1);
        int val = obh[b * NBINS + r] + (int)boffB[blockIdx.x];
        obh[b * NBINS + r] = val;
        if (b == 0) bucketbase[r] = val;
    }
    if (g == 0) bucketbase[NBINS] = N_EDGES;
}

// ---------------- radix phase 3: scatter packed (dst,src) into private segments ----------------
__global__ __launch_bounds__(256) void k_binwriteB(const int* __restrict__ src, const int* __restrict__ dst,
                                                   const int* __restrict__ obh,
                                                   unsigned long long* __restrict__ bpack) {
    __shared__ unsigned pos[NBINS];
    for (int r = threadIdx.x; r < NBINS; r += 256)
        pos[r] = (unsigned)obh[blockIdx.x * NBINS + r];
    __syncthreads();
    int base = blockIdx.x * CHUNKB;
    int end = base + CHUNKB; if (end > N_EDGES) end = N_EDGES;
    for (int e = base + threadIdx.x; e < end; e += 256) {
        int d = dst[e];
        unsigned p = atomicAdd(&pos[d >> 8], 1u);
        bpack[p] = ((unsigned long long)(unsigned)d << 32) | (unsigned)src[e];
    }
}

// ---------------- radix phase 4: per-bucket in-LDS CSR (rowptr + esrc), no global atomics ----------------
__global__ __launch_bounds__(256) void k_bucket_csr(const unsigned long long* __restrict__ bpack,
                                                    const int* __restrict__ bucketbase,
                                                    int* __restrict__ rowptr,
                                                    int* __restrict__ esrc) {
    __shared__ unsigned c[256];
    int b = blockIdx.x;
    int t = threadIdx.x;
    int bb = bucketbase[b], be = bucketbase[b + 1];
    c[t] = 0u;
    __syncthreads();
    // pass 1: local degree histogram
    for (int i = bb + t; i < be; i += 256)
        atomicAdd(&c[(unsigned)(bpack[i] >> 32) & 255u], 1u);
    __syncthreads();
    unsigned own = c[t];
    // inclusive scan over 256 local degrees
    for (int d = 1; d < 256; d <<= 1) {
        unsigned add = (t >= d) ? c[t - d] : 0u;
        __syncthreads();
        c[t] += add;
        __syncthreads();
    }
    unsigned excl = c[t] - own;
    int node = (b << 8) + t;
    if (node < N_NODES) rowptr[node] = bb + (int)excl;
    if (b == NBINS - 1 && t == 0) rowptr[N_NODES] = N_EDGES;
    __syncthreads();
    c[t] = excl;               // reuse as position cursors
    __syncthreads();
    // pass 2: scatter srcs into the bucket's dense esrc window (~16KB, bursty)
    for (int i = bb + t; i < be; i += 256) {
        unsigned long long p = bpack[i];
        unsigned slot = atomicAdd(&c[(unsigned)(p >> 32) & 255u], 1u);
        esrc[bb + (int)slot] = (int)(unsigned)p;
    }
}

// ---------------- mean aggregation ----------------
__global__ void k_aggregate(const unsigned short* __restrict__ feat,
                            const int* __restrict__ esrc,
                            const int* __restrict__ rowptr,
                            unsigned short* __restrict__ out) {
    int node = blockIdx.x * 4 + (threadIdx.x >> 6);
    if (node >= N_NODES) return;
    int lane = threadIdx.x & 63;
    int sub = lane >> 4;          // which of 4 concurrent edges
    int fl = lane & 15;           // feature lane: feats [fl*8, fl*8+8)
    int s = rowptr[node], e = rowptr[node + 1];
    float acc[8];
#pragma unroll
    for (int q = 0; q < 8; ++q) acc[q] = 0.f;

    for (int j = s + sub; j < e; j += 4) {
        int sv = esrc[j];
        short8 v = *(const short8*)(feat + (size_t)sv * FDIM + fl * 8);
#pragma unroll
        for (int q = 0; q < 8; ++q) acc[q] += bf2f((unsigned short)v[q]);
    }
#pragma unroll
    for (int q = 0; q < 8; ++q) {
        acc[q] += __shfl_xor(acc[q], 16, 64);
        acc[q] += __shfl_xor(acc[q], 32, 64);
    }
    int deg = e - s;
    float inv = 1.0f / (float)(deg > 1 ? deg : 1);
    if (sub == 0) {
        short8 o;
#pragma unroll
        for (int q = 0; q < 8; ++q) o[q] = (short)f2bf(acc[q] * inv);
        *(short8*)(out + (size_t)node * FDIM + fl * 8) = o;
    }
}

// ---------------- pack weights, k-major fragments ----------------
// Bp[k8][col][8]: B-frag loads (lanes 0..15 = consecutive cols) fully coalesced.
__global__ void k_pack(const float* __restrict__ Wl, const float* __restrict__ Wr,
                       const float* __restrict__ bin, unsigned short* __restrict__ Bp,
                       float* __restrict__ bout, int ncols_out, int ncols_src, int Keach) {
    int K = (Wr != nullptr) ? 2 * Keach : Keach;
    int idx = blockIdx.x * blockDim.x + threadIdx.x;
    if (idx >= ncols_out * K) return;
    int col = idx / K, k = idx % K;
    float v = 0.f;
    if (col < ncols_src)
        v = (k < Keach) ? Wl[(size_t)k * ncols_src + col]
                        : Wr[(size_t)(k - Keach) * ncols_src + col];
    Bp[((size_t)(k >> 3) * ncols_out + col) * 8 + (k & 7)] = f2bf(v);
    if (k == 0) bout[col] = (col < ncols_src) ? bin[col] : 0.f;
}

// ---------------- fused layer GEMM: out = relu([A0 | A1] @ W + bias), bf16 out ----------------
// Bp layout: [k8=32][col=128][8] bf16.
__global__ __launch_bounds__(256) void k_gemm_layer(
        const unsigned short* __restrict__ A0, const unsigned short* __restrict__ A1,
        const unsigned short* __restrict__ Bp, const float* __restrict__ bias,
        unsigned short* __restrict__ out) {
    int wave = threadIdx.x >> 6;
    int lane = threadIdx.x & 63;
    int rowblk = blockIdx.x * 64 + wave * 16;
    int lrow = lane & 15;
    int kgrp = lane >> 4;
    int arow = rowblk + lrow; if (arow > N_NODES - 1) arow = N_NODES - 1;

    f32x4 acc[8];
#pragma unroll
    for (int c = 0; c < 8; ++c) acc[c] = (f32x4){0.f, 0.f, 0.f, 0.f};

#pragma unroll
    for (int kb = 0; kb < 8; ++kb) {
        const unsigned short* Asrc = (kb < 4) ? A0 : A1;
        int kk = (kb & 3) * 32 + kgrp * 8;
        short8 a = *(const short8*)(Asrc + (size_t)arow * FDIM + kk);
        int k8 = kb * 4 + kgrp;
        const unsigned short* brow = Bp + ((size_t)k8 * FDIM + lrow) * 8;
#pragma unroll
        for (int c = 0; c < 8; ++c) {
            short8 b = *(const short8*)(brow + c * 16 * 8);
            acc[c] = __builtin_amdgcn_mfma_f32_16x16x32_bf16(a, b, acc[c], 0, 0, 0);
        }
    }

    int orowbase = rowblk + kgrp * 4;
#pragma unroll
    for (int c = 0; c < 8; ++c) {
        int col = c * 16 + lrow;
        float bv = bias[col];
#pragma unroll
        for (int i = 0; i < 4; ++i) {
            int r = orowbase + i;
            if (r < N_NODES) {
                float v = acc[c][i] + bv;
                v = fmaxf(v, 0.f);
                out[(size_t)r * FDIM + col] = f2bf(v);
            }
        }
    }
}

// ---------------- output GEMM: out = A0 @ W + bias, fp32 out [N][40] ----------------
// Bp layout: [k8=16][col=48][8] bf16.
__global__ __launch_bounds__(256) void k_gemm_out(
        const unsigned short* __restrict__ A0, const unsigned short* __restrict__ Bp,
        const float* __restrict__ bias, float* __restrict__ out) {
    int wave = threadIdx.x >> 6;
    int lane = threadIdx.x & 63;
    int rowblk = blockIdx.x * 64 + wave * 16;
    int lrow = lane & 15;
    int kgrp = lane >> 4;
    int arow = rowblk + lrow; if (arow > N_NODES - 1) arow = N_NODES - 1;

    f32x4 acc[3];
#pragma unroll
    for (int c = 0; c < 3; ++c) acc[c] = (f32x4){0.f, 0.f, 0.f, 0.f};

#pragma unroll
    for (int kb = 0; kb < 4; ++kb) {
        int kk = kb * 32 + kgrp * 8;
        short8 a = *(const short8*)(A0 + (size_t)arow * FDIM + kk);
        int k8 = kb * 4 + kgrp;
        const unsigned short* brow = Bp + ((size_t)k8 * NCLS_PAD + lrow) * 8;
#pragma unroll
        for (int c = 0; c < 3; ++c) {
            short8 b = *(const short8*)(brow + c * 16 * 8);
            acc[c] = __builtin_amdgcn_mfma_f32_16x16x32_bf16(a, b, acc[c], 0, 0, 0);
        }
    }

    int orowbase = rowblk + kgrp * 4;
#pragma unroll
    for (int c = 0; c < 3; ++c) {
        int col = c * 16 + lrow;
        if (col < NCLS) {
            float bv = bias[col];
#pragma unroll
            for (int i = 0; i < 4; ++i) {
                int r = orowbase + i;
                if (r < N_NODES)
                    out[(size_t)r * NCLS + col] = acc[c][i] + bv;
            }
        }
    }
}

extern "C" void kernel_launch(void* const* d_in, const int* in_sizes, int n_in,
                              void* d_out, int out_size, void* d_ws, size_t ws_size,
                              hipStream_t stream) {
    const float* x    = (const float*)d_in[0];
    const int*   ei   = (const int*)d_in[1];
    const float* W1l  = (const float*)d_in[2];
    const float* W1r  = (const float*)d_in[3];
    const float* b1   = (const float*)d_in[4];
    const float* W2l  = (const float*)d_in[5];
    const float* W2r  = (const float*)d_in[6];
    const float* b2   = (const float*)d_in[7];
    const float* Wout = (const float*)d_in[8];
    const float* bout = (const float*)d_in[9];
    const int* src = ei;
    const int* dst = ei + N_EDGES;

    char* ws = (char*)d_ws;
    size_t off = 0;
    auto alloc = [&](size_t bytes) -> void* {
        void* p = ws + off;
        off += (bytes + 255) & ~(size_t)255;
        return p;
    };
    unsigned short* xb   = (unsigned short*)alloc((size_t)N_NODES * FDIM * 2);
    unsigned short* aggn = (unsigned short*)alloc((size_t)N_NODES * FDIM * 2);
    unsigned short* h1   = (unsigned short*)alloc((size_t)N_NODES * FDIM * 2);
    unsigned short* h2   = (unsigned short*)alloc((size_t)N_NODES * FDIM * 2);
    unsigned short* Bp1  = (unsigned short*)alloc((size_t)FDIM * 256 * 2);
    unsigned short* Bp2  = (unsigned short*)alloc((size_t)FDIM * 256 * 2);
    unsigned short* Bp3  = (unsigned short*)alloc((size_t)NCLS_PAD * FDIM * 2);
    float* b1p = (float*)alloc(FDIM * 4);
    float* b2p = (float*)alloc(FDIM * 4);
    float* b3p = (float*)alloc(NCLS_PAD * 4);
    int* rowptr    = (int*)alloc((size_t)(N_NODES + 1) * 4);
    int* esrc      = (int*)alloc((size_t)N_EDGES * 4);
    int* bh        = (int*)alloc((size_t)NBLKB * NBINS * 4);
    int* obh       = (int*)alloc((size_t)NBLKB * NBINS * 4);
    int* bucketbase= (int*)alloc((size_t)(NBINS + 1) * 4);
    unsigned* bsumB = (unsigned*)alloc((size_t)SCANB_NB * 4);
    unsigned* boffB = (unsigned*)alloc((size_t)SCANB_NB * 4);
    unsigned long long* bpack = (unsigned long long*)alloc((size_t)N_EDGES * 8);

    // bf16 copy of x
    int n4 = N_NODES * FDIM / 4;
    k_cvt_bf16<<<(n4 + 255) / 256, 256, 0, stream>>>((const float4*)x, (ushort4*)xb, n4);

    // weight packs (k-major fragment layout)
    k_pack<<<(FDIM * 256 + 255) / 256, 256, 0, stream>>>(W1l, W1r, b1, Bp1, b1p, FDIM, FDIM, FDIM);
    k_pack<<<(FDIM * 256 + 255) / 256, 256, 0, stream>>>(W2l, W2r, b2, Bp2, b2p, FDIM, FDIM, FDIM);
    k_pack<<<(NCLS_PAD * FDIM + 255) / 256, 256, 0, stream>>>(Wout, nullptr, bout, Bp3, b3p, NCLS_PAD, NCLS, FDIM);

    // CSR build: 391-bucket radix partition + per-bucket in-LDS finish
    k_countB<<<NBLKB, 256, 0, stream>>>(dst, bh);
    k_scanB1<<<SCANB_NB, 1024, 0, stream>>>(bh, obh, bsumB);
    k_scanB2<<<1, 64, 0, stream>>>(bsumB, boffB);
    k_scanB3<<<SCANB_NB, 1024, 0, stream>>>(obh, boffB, bucketbase);
    k_binwriteB<<<NBLKB, 256, 0, stream>>>(src, dst, obh, bpack);
    k_bucket_csr<<<NBINS, 256, 0, stream>>>(bpack, bucketbase, rowptr, esrc);

    int aggGrid = (N_NODES + 3) / 4;
    int gemmGrid = (N_NODES + 63) / 64;

    // layer 1
    k_aggregate<<<aggGrid, 256, 0, stream>>>(xb, esrc, rowptr, aggn);
    k_gemm_layer<<<gemmGrid, 256, 0, stream>>>(aggn, xb, Bp1, b1p, h1);
    // layer 2
    k_aggregate<<<aggGrid, 256, 0, stream>>>(h1, esrc, rowptr, aggn);
    k_gemm_layer<<<gemmGrid, 256, 0, stream>>>(aggn, h1, Bp2, b2p, h2);
    // head
    k_gemm_out<<<gemmGrid, 256, 0, stream>>>(h2, Bp3, b3p, (float*)d_out);
}